// Round 9
// baseline (276.968 us; speedup 1.0000x reference)
//
#include <hip/hip_runtime.h>

typedef unsigned short u16;
typedef unsigned int uint;
typedef __attribute__((ext_vector_type(8))) short bf16x8;
typedef __attribute__((ext_vector_type(4))) float f32x4;

#define NBATCH 16
#define SDIM   1024
#define INDIM  512
#define OUTDIM 512
#define HEADS  8
#define DHEAD  64
#define MROWS  (NBATCH * SDIM)   // 16384
#define KDIM   512
// 1/sqrt(64) * log2(e): scores come out of MFMA pre-scaled for exp2
#define QSCALE (0.125f * 1.44269504088896340736f)

__device__ __forceinline__ u16 f2bf(float f) {
  union { float f; uint u; } v; v.f = f;
  uint u = v.u;
  return (u16)((u + 0x7FFFu + ((u >> 16) & 1u)) >> 16);  // RNE
}

__device__ __forceinline__ uint pkbf(float a, float b) {  // 2xf32 -> packed bf16x2 RNE
  return (uint)f2bf(a) | ((uint)f2bf(b) << 16);
}

// fast pack: round-half-up (+0x8000) then v_perm_b32 grabs both high halves
__device__ __forceinline__ uint pkbf_fast(float a, float b) {
  union { float f; uint u; } ua, ub; ua.f = a; ub.f = b;
  return __builtin_amdgcn_perm(ub.u + 0x8000u, ua.u + 0x8000u, 0x07060302);
}

__device__ __forceinline__ float bf2f(u16 v) {
  union { uint u; float f; } c; c.u = (uint)v << 16;
  return c.f;
}

__device__ __forceinline__ void gload16(const void* g, void* l) {
  __builtin_amdgcn_global_load_lds(
      (const __attribute__((address_space(1))) uint*)g,
      (__attribute__((address_space(3))) uint*)l, 16, 0, 0);
}

// ---------------------------------------------------------------- prep
__global__ __launch_bounds__(256) void prep_kernel(
    const float* __restrict__ x, const float* __restrict__ wq,
    const float* __restrict__ wk, const float* __restrict__ wv,
    const float* __restrict__ w_out,
    u16* __restrict__ xb, u16* __restrict__ W1T, u16* __restrict__ W2T) {
  int gid = blockIdx.x * blockDim.x + threadIdx.x;
  int stride = gridDim.x * blockDim.x;
  const int NX4 = MROWS * INDIM / 4;
  for (int i = gid; i < NX4; i += stride) {
    float4 v = ((const float4*)x)[i];
    ((ushort4*)xb)[i] = make_ushort4(f2bf(v.x), f2bf(v.y), f2bf(v.z), f2bf(v.w));
  }
  for (int i = gid; i < 3 * OUTDIM * INDIM; i += stride) {
    int n = i >> 9, f = i & 511;
    int proj = n >> 9, hd = n & 511, h = hd >> 6, d = hd & 63;
    const float* src = (proj == 0) ? wq : (proj == 1) ? wk : wv;
    float val = src[(h * INDIM + f) * DHEAD + d];
    if (proj == 0) val *= QSCALE;
    W1T[i] = f2bf(val);
  }
  for (int i = gid; i < OUTDIM * INDIM; i += stride) {
    int n = i >> 9, f = i & 511;
    W2T[i] = f2bf(w_out[f * OUTDIM + n]);
  }
}

// ---------------------------------------------------------------- GEMM 128x128, BK=32
template <int EPI>
__global__ __launch_bounds__(256) void gemm128(
    const u16* __restrict__ A, const u16* __restrict__ Bt,
    u16* __restrict__ Qb, u16* __restrict__ Kb, u16* __restrict__ VTb,
    float* __restrict__ Y) {
  __shared__ u16 As[128 * 32];
  __shared__ u16 Bs[128 * 32];
  const int tid = threadIdx.x;
  const int w = tid >> 6, lane = tid & 63;
  const int quad = lane >> 4, ln = lane & 15;
  const int wm = w >> 1, wn = w & 1;
  const int m0 = blockIdx.y * 128, n0 = blockIdx.x * 128;

  f32x4 zero4 = {0.f, 0.f, 0.f, 0.f};
  f32x4 acc[4][4];
  for (int i = 0; i < 4; i++)
    for (int j = 0; j < 4; j++) acc[i][j] = zero4;

  const char* Ag = (const char*)(A + (size_t)m0 * KDIM);
  const char* Bg = (const char*)(Bt + (size_t)n0 * KDIM);
  const int r0 = w * 16 + (lane >> 2);
  const int cb = (lane & 3) * 16;

  for (int kk = 0; kk < KDIM; kk += 32) {
    __syncthreads();
    gload16(Ag + (size_t)r0 * (KDIM * 2) + kk * 2 + cb, (char*)As + w * 1024);
    gload16(Ag + (size_t)(r0 + 64) * (KDIM * 2) + kk * 2 + cb, (char*)As + 4096 + w * 1024);
    gload16(Bg + (size_t)r0 * (KDIM * 2) + kk * 2 + cb, (char*)Bs + w * 1024);
    gload16(Bg + (size_t)(r0 + 64) * (KDIM * 2) + kk * 2 + cb, (char*)Bs + 4096 + w * 1024);
    __syncthreads();
    bf16x8 af[4], bfr[4];
    for (int mt = 0; mt < 4; mt++)
      af[mt] = *(const bf16x8*)&As[(wm * 64 + mt * 16 + ln) * 32 + quad * 8];
    for (int nt = 0; nt < 4; nt++)
      bfr[nt] = *(const bf16x8*)&Bs[(wn * 64 + nt * 16 + ln) * 32 + quad * 8];
    for (int mt = 0; mt < 4; mt++)
      for (int nt = 0; nt < 4; nt++)
        acc[mt][nt] = __builtin_amdgcn_mfma_f32_16x16x32_bf16(af[mt], bfr[nt], acc[mt][nt], 0, 0, 0);
  }

  for (int mt = 0; mt < 4; mt++) {
    int mbase = m0 + wm * 64 + mt * 16 + quad * 4;
    int b = mbase >> 10, sbase = mbase & 1023;
    for (int nt = 0; nt < 4; nt++) {
      f32x4 c = acc[mt][nt];
      int col = n0 + wn * 64 + nt * 16 + ln;
      if (EPI == 0) {
        int proj = n0 >> 9;
        int hd = col & 511, h = hd >> 6, d = hd & 63;
        if (proj == 2) {
          *(ushort4*)&VTb[((size_t)(h * 16 + b) * 64 + d) * 1024 + sbase] =
              make_ushort4(f2bf(c[0]), f2bf(c[1]), f2bf(c[2]), f2bf(c[3]));
        } else {
          u16* dst = (proj == 0) ? Qb : Kb;
          size_t base = ((size_t)(h * 16 + b) * 1024) * 64 + d;
          dst[base + (size_t)(sbase + 0) * 64] = f2bf(c[0]);
          dst[base + (size_t)(sbase + 1) * 64] = f2bf(c[1]);
          dst[base + (size_t)(sbase + 2) * 64] = f2bf(c[2]);
          dst[base + (size_t)(sbase + 3) * 64] = f2bf(c[3]);
        }
      } else {
        Y[(size_t)(mbase + 0) * OUTDIM + col] = c[0];
        Y[(size_t)(mbase + 1) * OUTDIM + col] = c[1];
        Y[(size_t)(mbase + 2) * OUTDIM + col] = c[2];
        Y[(size_t)(mbase + 3) * OUTDIM + col] = c[3];
      }
    }
  }
}

// ---------------------------------------------------------------- attnA v4 (unchanged)
__global__ __launch_bounds__(512, 4) void attnA_kernel(
    const u16* __restrict__ Qb, const u16* __restrict__ Kb,
    u16* __restrict__ LinvX) {
  __shared__ u16 Qt[2 * 64 * 64];    // 16 KB
  __shared__ u16 Kt[2 * 256 * 64];   // 64 KB
  const int tid = threadIdx.x;
  const int w = tid >> 6, lane = tid & 63;
  const int quad = lane >> 4, ln = lane & 15;
  const int ws = w & 3, wt = w >> 2;
  const int h = blockIdx.x & 7;
  const int s0 = ((blockIdx.x >> 3) & 15) * 64;
  const int tq = blockIdx.x >> 7;
  const int t0 = tq * 256;
  const int srow = tid >> 3, sseg = tid & 7;

  const u16* Qh = Qb + (size_t)h * 16 * 65536;
  const u16* Kh = Kb + (size_t)h * 16 * 65536;

  f32x4 zero4 = {0.f, 0.f, 0.f, 0.f};
  f32x4 Lacc[8];
  for (int i = 0; i < 8; i++) Lacc[i] = zero4;

  // prime b=0 into buf 0
  {
    gload16(Qh + (size_t)(s0 + srow) * 64 + sseg * 8, (char*)Qt + w * 1024);
    const u16* Kg = Kh + (size_t)(t0 + srow) * 64 + sseg * 8;
    gload16(Kg,            (char*)Kt + w * 1024);
    gload16(Kg + 64 * 64,  (char*)Kt + 8192 + w * 1024);
    gload16(Kg + 128 * 64, (char*)Kt + 16384 + w * 1024);
    gload16(Kg + 192 * 64, (char*)Kt + 24576 + w * 1024);
  }

  for (int b = 0; b < 16; b++) {
    const int cur = b & 1;
    __syncthreads();   // drains buf[cur] loads; releases buf[cur^1] readers
    if (b < 15) {
      const u16* Qg = Qh + (size_t)(b + 1) * 65536 + (size_t)(s0 + srow) * 64 + sseg * 8;
      const u16* Kg = Kh + (size_t)(b + 1) * 65536 + (size_t)(t0 + srow) * 64 + sseg * 8;
      char* Kd = (char*)Kt + (cur ^ 1) * 32768 + w * 1024;
      gload16(Qg, (char*)Qt + (cur ^ 1) * 8192 + w * 1024);
      gload16(Kg,            Kd);
      gload16(Kg + 64 * 64,  Kd + 8192);
      gload16(Kg + 128 * 64, Kd + 16384);
      gload16(Kg + 192 * 64, Kd + 24576);
    }
    const u16* Qr = &Qt[cur * 4096 + (ws * 16 + ln) * 64];
    bf16x8 q0 = *(const bf16x8*)&Qr[quad * 8];
    bf16x8 q1 = *(const bf16x8*)&Qr[32 + quad * 8];
    for (int tsub = 0; tsub < 8; tsub++) {
      const u16* Kr = &Kt[cur * 16384 + (wt * 128 + tsub * 16 + ln) * 64];
      f32x4 cc = zero4;
      cc = __builtin_amdgcn_mfma_f32_16x16x32_bf16(*(const bf16x8*)&Kr[quad * 8], q0, cc, 0, 0, 0);
      cc = __builtin_amdgcn_mfma_f32_16x16x32_bf16(*(const bf16x8*)&Kr[32 + quad * 8], q1, cc, 0, 0, 0);
      f32x4 L = Lacc[tsub];
      L[0] += __builtin_amdgcn_exp2f(cc[0]); L[1] += __builtin_amdgcn_exp2f(cc[1]);
      L[2] += __builtin_amdgcn_exp2f(cc[2]); L[3] += __builtin_amdgcn_exp2f(cc[3]);
      Lacc[tsub] = L;
    }
  }

  // epilogue: LinvX[h][tc(64)][s(1024)][16] ; lane holds (s=ln, t=quad*4+r)
  const int sg = s0 + ws * 16 + ln;
  for (int tsub = 0; tsub < 8; tsub++) {
    const int tc = tq * 16 + wt * 8 + tsub;
    f32x4 L = Lacc[tsub];
    uint2 pk = make_uint2(
        pkbf(__builtin_amdgcn_rcpf(L[0]), __builtin_amdgcn_rcpf(L[1])),
        pkbf(__builtin_amdgcn_rcpf(L[2]), __builtin_amdgcn_rcpf(L[3])));
    *(uint2*)&LinvX[(((size_t)(h * 64 + tc)) * 1024 + sg) * 16 + quad * 4] = pk;
  }
}

// ---------------------------------------------------------------- attnB v5 = v3 structure, s64 grid
// P = exp2 * Linv, O = P.V. grid 2048 = h(&7) x 16 b x 16 s64-tiles. Block
// 256 = 4 waves x s16. v3's proven LDS layout/swizzles; per-wave Pp tile
// halves (one s16 subtile per wave) -> 21.3 KB LDS -> 7 blocks/CU resident
// (was 4): barrier-drain stalls get covered by other blocks' waves. Linv
// loads hoisted to iter top to overlap global latency with LDS reads.
__global__ __launch_bounds__(256, 8) void attnB_kernel(
    const u16* __restrict__ Qb, const u16* __restrict__ Kb,
    const u16* __restrict__ VTb, const u16* __restrict__ LinvX,
    u16* __restrict__ hc) {
  __shared__ u16 Ks[2 * 32 * 64];   // 8 KB
  __shared__ u16 Vs[2 * 64 * 32];   // 8 KB
  __shared__ u16 Pp[4 * 16 * 40];   // 5 KB, one tile per wave
  const int tid = threadIdx.x;
  const int w = tid >> 6, lane = tid & 63;
  const int quad = lane >> 4, ln = lane & 15;
  const int h = blockIdx.x & 7, b = (blockIdx.x >> 3) & 15, sblk = blockIdx.x >> 7;
  const int ss0 = sblk * 64 + w * 16;
  const int krow = tid >> 3;
  const int ksw = ((tid & 7) ^ (krow & 7)) * 8;          // K staging swizzle
  const int vrow = tid >> 2;
  const int vsw = ((tid & 3) ^ ((tid >> 3) & 3)) * 8;    // V staging swizzle

  const u16* Kbase = Kb + (size_t)(h * 16 + b) * 65536;
  const u16* Vbase = VTb + (size_t)(h * 16 + b) * 65536;
  const u16* LinvH = LinvX + (size_t)h * 64 * 1024 * 16;

  f32x4 zero4 = {0.f, 0.f, 0.f, 0.f};
  bf16x8 qf0, qf1;
  {
    const u16* Qp = Qb + ((size_t)(h * 16 + b) * 1024 + ss0 + ln) * 64;
    qf0 = *(const bf16x8*)&Qp[quad * 8];
    qf1 = *(const bf16x8*)&Qp[32 + quad * 8];
  }
  f32x4 o[4];
  for (int df = 0; df < 4; df++) o[df] = zero4;

  // prime it=0 into buf 0
  gload16(Kbase + (size_t)krow * 64 + ksw, (char*)Ks + w * 1024);
  gload16(Vbase + (size_t)vrow * 1024 + vsw, (char*)Vs + w * 1024);

  const int fsw = (quad ^ (ln & 7)) * 8;            // K fragment swizzle
  const int vfsw = (quad ^ ((ln >> 1) & 3)) * 8;    // V fragment swizzle
  u16* PpW = &Pp[w * 640 + ln * 40];

  for (int it = 0; it < 32; ++it) {
    const int cur = it & 1;
    const int t0 = it * 32;
    __syncthreads();   // drains buf[cur] loads; releases buf[cur^1] readers
    if (it < 31) {
      gload16(Kbase + (size_t)(t0 + 32 + krow) * 64 + ksw,
              (char*)Ks + (cur ^ 1) * 4096 + w * 1024);
      gload16(Vbase + (size_t)vrow * 1024 + t0 + 32 + vsw,
              (char*)Vs + (cur ^ 1) * 4096 + w * 1024);
    }
    // hoisted Linv loads (global; overlap with LDS fragment reads below)
    ushort4 lin[2];
    for (int tsub = 0; tsub < 2; tsub++)
      lin[tsub] = *(const ushort4*)&LinvH[
          (((size_t)(it * 2 + tsub)) * 1024 + ss0 + ln) * 16 + quad * 4];

    bf16x8 kf[2][2], vf[4];
    for (int tsub = 0; tsub < 2; tsub++) {
      const u16* Kr = &Ks[cur * 2048 + (tsub * 16 + ln) * 64];
      kf[tsub][0] = *(const bf16x8*)&Kr[fsw];
      kf[tsub][1] = *(const bf16x8*)&Kr[fsw ^ 32];
    }
    for (int df = 0; df < 4; df++)
      vf[df] = *(const bf16x8*)&Vs[cur * 2048 + (df * 16 + ln) * 32 + vfsw];

    for (int tsub = 0; tsub < 2; tsub++) {
      f32x4 cc = zero4;
      cc = __builtin_amdgcn_mfma_f32_16x16x32_bf16(kf[tsub][0], qf0, cc, 0, 0, 0);
      cc = __builtin_amdgcn_mfma_f32_16x16x32_bf16(kf[tsub][1], qf1, cc, 0, 0, 0);
      float p0 = __builtin_amdgcn_exp2f(cc[0]) * bf2f(lin[tsub].x);
      float p1 = __builtin_amdgcn_exp2f(cc[1]) * bf2f(lin[tsub].y);
      float p2 = __builtin_amdgcn_exp2f(cc[2]) * bf2f(lin[tsub].z);
      float p3 = __builtin_amdgcn_exp2f(cc[3]) * bf2f(lin[tsub].w);
      *(uint2*)&PpW[tsub * 16 + quad * 4] = make_uint2(pkbf_fast(p0, p1), pkbf_fast(p2, p3));
    }
    bf16x8 pa = *(const bf16x8*)&PpW[quad * 8];  // wave-private: no barrier
    for (int df = 0; df < 4; df++)
      o[df] = __builtin_amdgcn_mfma_f32_16x16x32_bf16(pa, vf[df], o[df], 0, 0, 0);
  }

  // epilogue: heads_cat [b*1024+s][h*64+d] bf16
  for (int df = 0; df < 4; df++) {
    f32x4 c = o[df];
    for (int r = 0; r < 4; r++) {
      int sg = ss0 + quad * 4 + r;
      hc[((size_t)(b * 1024 + sg)) * 512 + h * 64 + df * 16 + ln] = f2bf(c[r]);
    }
  }
}

// ---------------------------------------------------------------- bias + LN + LeakyReLU
__global__ __launch_bounds__(256) void ln_kernel(
    const float* __restrict__ Y, const float* __restrict__ b_out,
    const float* __restrict__ gamma, const float* __restrict__ beta,
    float* __restrict__ out) {
  const int w = threadIdx.x >> 6, lane = threadIdx.x & 63;
  const int row = blockIdx.x * 4 + w;
  const float4* yr = (const float4*)(Y + (size_t)row * 512);
  float4 v0 = yr[lane], v1 = yr[64 + lane];
  float4 b0 = ((const float4*)b_out)[lane], b1 = ((const float4*)b_out)[64 + lane];
  v0.x += b0.x; v0.y += b0.y; v0.z += b0.z; v0.w += b0.w;
  v1.x += b1.x; v1.y += b1.y; v1.z += b1.z; v1.w += b1.w;
  float s  = v0.x + v0.y + v0.z + v0.w + v1.x + v1.y + v1.z + v1.w;
  float s2 = v0.x * v0.x + v0.y * v0.y + v0.z * v0.z + v0.w * v0.w +
             v1.x * v1.x + v1.y * v1.y + v1.z * v1.z + v1.w * v1.w;
  for (int off = 32; off; off >>= 1) {
    s += __shfl_xor(s, off);
    s2 += __shfl_xor(s2, off);
  }
  float mean = s * (1.0f / 512.0f);
  float var = s2 * (1.0f / 512.0f) - mean * mean;
  float rs = rsqrtf(var + 1e-5f);
  float4 g0 = ((const float4*)gamma)[lane], g1 = ((const float4*)gamma)[64 + lane];
  float4 e0 = ((const float4*)beta)[lane], e1 = ((const float4*)beta)[64 + lane];
  float4 o0, o1;
  o0.x = (v0.x - mean) * rs * g0.x + e0.x;  o0.y = (v0.y - mean) * rs * g0.y + e0.y;
  o0.z = (v0.z - mean) * rs * g0.z + e0.z;  o0.w = (v0.w - mean) * rs * g0.w + e0.w;
  o1.x = (v1.x - mean) * rs * g1.x + e1.x;  o1.y = (v1.y - mean) * rs * g1.y + e1.y;
  o1.z = (v1.z - mean) * rs * g1.z + e1.z;  o1.w = (v1.w - mean) * rs * g1.w + e1.w;
  o0.x = o0.x >= 0.f ? o0.x : 0.1f * o0.x;  o0.y = o0.y >= 0.f ? o0.y : 0.1f * o0.y;
  o0.z = o0.z >= 0.f ? o0.z : 0.1f * o0.z;  o0.w = o0.w >= 0.f ? o0.w : 0.1f * o0.w;
  o1.x = o1.x >= 0.f ? o1.x : 0.1f * o1.x;  o1.y = o1.y >= 0.f ? o1.y : 0.1f * o1.y;
  o1.z = o1.z >= 0.f ? o1.z : 0.1f * o1.z;  o1.w = o1.w >= 0.f ? o1.w : 0.1f * o1.w;
  ((float4*)out)[(size_t)row * 128 + lane] = o0;
  ((float4*)out)[(size_t)row * 128 + 64 + lane] = o1;
}

// ---------------------------------------------------------------- launch
extern "C" void kernel_launch(void* const* d_in, const int* in_sizes, int n_in,
                              void* d_out, int out_size, void* d_ws, size_t ws_size,
                              hipStream_t stream) {
  const float* x      = (const float*)d_in[0];
  const float* wq     = (const float*)d_in[1];
  const float* wk     = (const float*)d_in[2];
  const float* wv     = (const float*)d_in[3];
  const float* w_out  = (const float*)d_in[4];
  const float* b_out  = (const float*)d_in[5];
  const float* gamma  = (const float*)d_in[6];
  const float* beta   = (const float*)d_in[7];
  float* out = (float*)d_out;

  char* ws = (char*)d_ws;
  size_t off = 0;
  u16* xb  = (u16*)(ws + off); off += (size_t)MROWS * INDIM * 2;
  u16* W1T = (u16*)(ws + off); off += (size_t)3 * OUTDIM * INDIM * 2;
  u16* W2T = (u16*)(ws + off); off += (size_t)OUTDIM * INDIM * 2;
  u16* Qb  = (u16*)(ws + off); off += (size_t)HEADS * NBATCH * SDIM * DHEAD * 2;
  u16* Kb  = (u16*)(ws + off); off += (size_t)HEADS * NBATCH * SDIM * DHEAD * 2;
  u16* VTb = (u16*)(ws + off); off += (size_t)HEADS * NBATCH * SDIM * DHEAD * 2;
  u16* hc  = (u16*)(ws + off); off += (size_t)MROWS * OUTDIM * 2;
  float* Yv = (float*)(ws + off);       // 33.5 MB, written by gemm2 AFTER attnB
  u16* LinvX = (u16*)Yv;                // 16.8 MB, aliased: used only attnA->attnB

  prep_kernel<<<2048, 256, 0, stream>>>(x, wq, wk, wv, w_out, xb, W1T, W2T);
  gemm128<0><<<dim3(12, 128), 256, 0, stream>>>(xb, W1T, Qb, Kb, VTb, nullptr);
  attnA_kernel<<<512, 512, 0, stream>>>(Qb, Kb, LinvX);
  attnB_kernel<<<2048, 256, 0, stream>>>(Qb, Kb, VTb, LinvX, hc);
  gemm128<1><<<dim3(4, 128), 256, 0, stream>>>(hc, W2T, nullptr, nullptr, nullptr, Yv);
  ln_kernel<<<4096, 256, 0, stream>>>(Yv, b_out, gamma, beta, out);
}

// Round 11
// 249.466 us; speedup vs baseline: 1.1102x; 1.1102x over previous
//
#include <hip/hip_runtime.h>

typedef unsigned short u16;
typedef unsigned int uint;
typedef __attribute__((ext_vector_type(8))) short bf16x8;
typedef __attribute__((ext_vector_type(4))) float f32x4;

#define NBATCH 16
#define SDIM   1024
#define INDIM  512
#define OUTDIM 512
#define HEADS  8
#define DHEAD  64
#define MROWS  (NBATCH * SDIM)   // 16384
#define KDIM   512
// 1/sqrt(64) * log2(e): scores come out of MFMA pre-scaled for exp2
#define QSCALE (0.125f * 1.44269504088896340736f)

__device__ __forceinline__ u16 f2bf(float f) {
  union { float f; uint u; } v; v.f = f;
  uint u = v.u;
  return (u16)((u + 0x7FFFu + ((u >> 16) & 1u)) >> 16);  // RNE
}

__device__ __forceinline__ uint pkbf(float a, float b) {  // 2xf32 -> packed bf16x2 RNE
  return (uint)f2bf(a) | ((uint)f2bf(b) << 16);
}

// fast pack: round-half-up (+0x8000) then v_perm_b32 grabs both high halves
__device__ __forceinline__ uint pkbf_fast(float a, float b) {
  union { float f; uint u; } ua, ub; ua.f = a; ub.f = b;
  return __builtin_amdgcn_perm(ub.u + 0x8000u, ua.u + 0x8000u, 0x07060302);
}

__device__ __forceinline__ float bf2f(u16 v) {
  union { uint u; float f; } c; c.u = (uint)v << 16;
  return c.f;
}

__device__ __forceinline__ void gload16(const void* g, void* l) {
  __builtin_amdgcn_global_load_lds(
      (const __attribute__((address_space(1))) uint*)g,
      (__attribute__((address_space(3))) uint*)l, 16, 0, 0);
}

// ---------------------------------------------------------------- prep
// blocks [0,2048): x fp32->bf16 (coalesced float4). blocks [2048,2304):
// LDS-tiled 64x64 weight transposes (coalesced reads AND writes; stride-65
// LDS kills bank conflicts).
__global__ __launch_bounds__(256) void prep_kernel(
    const float* __restrict__ x, const float* __restrict__ wq,
    const float* __restrict__ wk, const float* __restrict__ wv,
    const float* __restrict__ w_out,
    u16* __restrict__ xb, u16* __restrict__ W1T, u16* __restrict__ W2T) {
  __shared__ float T[64 * 65];
  const int tid = threadIdx.x;
  if (blockIdx.x < 2048) {
    const int NX4 = MROWS * INDIM / 4;
    int stride = 2048 * 256;
    for (int i = blockIdx.x * 256 + tid; i < NX4; i += stride) {
      float4 v = ((const float4*)x)[i];
      ((ushort4*)xb)[i] = make_ushort4(f2bf(v.x), f2bf(v.y), f2bf(v.z), f2bf(v.w));
    }
    return;
  }
  const int t = blockIdx.x - 2048;
  const int rr = tid >> 6, cc = tid & 63;
  if (t < 192) {
    // W1T[n=proj*512+h*64+d][f] <- src[h][f][d] (*QSCALE for wq)
    int proj = t >> 6, h = (t >> 3) & 7, f0 = (t & 7) * 64;
    const float* src = (proj == 0) ? wq : (proj == 1) ? wk : wv;
    float scale = (proj == 0) ? QSCALE : 1.0f;
    for (int it = 0; it < 16; it++) {
      int fi = it * 4 + rr;
      T[fi * 65 + cc] = src[((size_t)h * 512 + f0 + fi) * 64 + cc] * scale;
    }
    __syncthreads();
    u16* dst = W1T + ((size_t)(proj * 512 + h * 64)) * 512 + f0;
    for (int it = 0; it < 16; it++) {
      int d = it * 4 + rr;
      dst[(size_t)d * 512 + cc] = f2bf(T[cc * 65 + d]);
    }
  } else {
    // W2T[n][f] <- w_out[f][n]
    int t2 = t - 192;
    int n0 = (t2 >> 3) * 64, f0 = (t2 & 7) * 64;
    for (int it = 0; it < 16; it++) {
      int fi = it * 4 + rr;
      T[fi * 65 + cc] = w_out[(size_t)(f0 + fi) * 512 + n0 + cc];
    }
    __syncthreads();
    for (int it = 0; it < 16; it++) {
      int ni = it * 4 + rr;
      W2T[(size_t)(n0 + ni) * 512 + f0 + cc] = f2bf(T[cc * 65 + ni]);
    }
  }
}

// ---------------------------------------------------------------- GEMM 128x128, BK=32
// EPI 0: QKV scatter epilogue (bf16). EPI 1: bf16 Y store (feeds ln).
template <int EPI>
__global__ __launch_bounds__(256) void gemm128(
    const u16* __restrict__ A, const u16* __restrict__ Bt,
    u16* __restrict__ Qb, u16* __restrict__ Kb, u16* __restrict__ VTb,
    u16* __restrict__ Yb) {
  __shared__ u16 As[128 * 32];
  __shared__ u16 Bs[128 * 32];
  const int tid = threadIdx.x;
  const int w = tid >> 6, lane = tid & 63;
  const int quad = lane >> 4, ln = lane & 15;
  const int wm = w >> 1, wn = w & 1;
  const int m0 = blockIdx.y * 128, n0 = blockIdx.x * 128;

  f32x4 zero4 = {0.f, 0.f, 0.f, 0.f};
  f32x4 acc[4][4];
  for (int i = 0; i < 4; i++)
    for (int j = 0; j < 4; j++) acc[i][j] = zero4;

  const char* Ag = (const char*)(A + (size_t)m0 * KDIM);
  const char* Bg = (const char*)(Bt + (size_t)n0 * KDIM);
  const int r0 = w * 16 + (lane >> 2);
  const int cb = (lane & 3) * 16;

  for (int kk = 0; kk < KDIM; kk += 32) {
    __syncthreads();
    gload16(Ag + (size_t)r0 * (KDIM * 2) + kk * 2 + cb, (char*)As + w * 1024);
    gload16(Ag + (size_t)(r0 + 64) * (KDIM * 2) + kk * 2 + cb, (char*)As + 4096 + w * 1024);
    gload16(Bg + (size_t)r0 * (KDIM * 2) + kk * 2 + cb, (char*)Bs + w * 1024);
    gload16(Bg + (size_t)(r0 + 64) * (KDIM * 2) + kk * 2 + cb, (char*)Bs + 4096 + w * 1024);
    __syncthreads();
    bf16x8 af[4], bfr[4];
    for (int mt = 0; mt < 4; mt++)
      af[mt] = *(const bf16x8*)&As[(wm * 64 + mt * 16 + ln) * 32 + quad * 8];
    for (int nt = 0; nt < 4; nt++)
      bfr[nt] = *(const bf16x8*)&Bs[(wn * 64 + nt * 16 + ln) * 32 + quad * 8];
    for (int mt = 0; mt < 4; mt++)
      for (int nt = 0; nt < 4; nt++)
        acc[mt][nt] = __builtin_amdgcn_mfma_f32_16x16x32_bf16(af[mt], bfr[nt], acc[mt][nt], 0, 0, 0);
  }

  for (int mt = 0; mt < 4; mt++) {
    int mbase = m0 + wm * 64 + mt * 16 + quad * 4;
    int b = mbase >> 10, sbase = mbase & 1023;
    for (int nt = 0; nt < 4; nt++) {
      f32x4 c = acc[mt][nt];
      int col = n0 + wn * 64 + nt * 16 + ln;
      if (EPI == 0) {
        int proj = n0 >> 9;
        int hd = col & 511, h = hd >> 6, d = hd & 63;
        if (proj == 2) {
          *(ushort4*)&VTb[((size_t)(h * 16 + b) * 64 + d) * 1024 + sbase] =
              make_ushort4(f2bf(c[0]), f2bf(c[1]), f2bf(c[2]), f2bf(c[3]));
        } else {
          u16* dst = (proj == 0) ? Qb : Kb;
          size_t base = ((size_t)(h * 16 + b) * 1024) * 64 + d;
          dst[base + (size_t)(sbase + 0) * 64] = f2bf(c[0]);
          dst[base + (size_t)(sbase + 1) * 64] = f2bf(c[1]);
          dst[base + (size_t)(sbase + 2) * 64] = f2bf(c[2]);
          dst[base + (size_t)(sbase + 3) * 64] = f2bf(c[3]);
        }
      } else {
        Yb[(size_t)(mbase + 0) * OUTDIM + col] = f2bf(c[0]);
        Yb[(size_t)(mbase + 1) * OUTDIM + col] = f2bf(c[1]);
        Yb[(size_t)(mbase + 2) * OUTDIM + col] = f2bf(c[2]);
        Yb[(size_t)(mbase + 3) * OUTDIM + col] = f2bf(c[3]);
      }
    }
  }
}

// ---------------------------------------------------------------- attnA v4 (proven, unchanged)
__global__ __launch_bounds__(512, 4) void attnA_kernel(
    const u16* __restrict__ Qb, const u16* __restrict__ Kb,
    u16* __restrict__ LinvX) {
  __shared__ u16 Qt[2 * 64 * 64];    // 16 KB
  __shared__ u16 Kt[2 * 256 * 64];   // 64 KB
  const int tid = threadIdx.x;
  const int w = tid >> 6, lane = tid & 63;
  const int quad = lane >> 4, ln = lane & 15;
  const int ws = w & 3, wt = w >> 2;
  const int h = blockIdx.x & 7;
  const int s0 = ((blockIdx.x >> 3) & 15) * 64;
  const int tq = blockIdx.x >> 7;
  const int t0 = tq * 256;
  const int srow = tid >> 3, sseg = tid & 7;

  const u16* Qh = Qb + (size_t)h * 16 * 65536;
  const u16* Kh = Kb + (size_t)h * 16 * 65536;

  f32x4 zero4 = {0.f, 0.f, 0.f, 0.f};
  f32x4 Lacc[8];
  for (int i = 0; i < 8; i++) Lacc[i] = zero4;

  // prime b=0 into buf 0
  {
    gload16(Qh + (size_t)(s0 + srow) * 64 + sseg * 8, (char*)Qt + w * 1024);
    const u16* Kg = Kh + (size_t)(t0 + srow) * 64 + sseg * 8;
    gload16(Kg,            (char*)Kt + w * 1024);
    gload16(Kg + 64 * 64,  (char*)Kt + 8192 + w * 1024);
    gload16(Kg + 128 * 64, (char*)Kt + 16384 + w * 1024);
    gload16(Kg + 192 * 64, (char*)Kt + 24576 + w * 1024);
  }

  for (int b = 0; b < 16; b++) {
    const int cur = b & 1;
    __syncthreads();   // drains buf[cur] loads; releases buf[cur^1] readers
    if (b < 15) {
      const u16* Qg = Qh + (size_t)(b + 1) * 65536 + (size_t)(s0 + srow) * 64 + sseg * 8;
      const u16* Kg = Kh + (size_t)(b + 1) * 65536 + (size_t)(t0 + srow) * 64 + sseg * 8;
      char* Kd = (char*)Kt + (cur ^ 1) * 32768 + w * 1024;
      gload16(Qg, (char*)Qt + (cur ^ 1) * 8192 + w * 1024);
      gload16(Kg,            Kd);
      gload16(Kg + 64 * 64,  Kd + 8192);
      gload16(Kg + 128 * 64, Kd + 16384);
      gload16(Kg + 192 * 64, Kd + 24576);
    }
    const u16* Qr = &Qt[cur * 4096 + (ws * 16 + ln) * 64];
    bf16x8 q0 = *(const bf16x8*)&Qr[quad * 8];
    bf16x8 q1 = *(const bf16x8*)&Qr[32 + quad * 8];
    for (int tsub = 0; tsub < 8; tsub++) {
      const u16* Kr = &Kt[cur * 16384 + (wt * 128 + tsub * 16 + ln) * 64];
      f32x4 cc = zero4;
      cc = __builtin_amdgcn_mfma_f32_16x16x32_bf16(*(const bf16x8*)&Kr[quad * 8], q0, cc, 0, 0, 0);
      cc = __builtin_amdgcn_mfma_f32_16x16x32_bf16(*(const bf16x8*)&Kr[32 + quad * 8], q1, cc, 0, 0, 0);
      f32x4 L = Lacc[tsub];
      L[0] += __builtin_amdgcn_exp2f(cc[0]); L[1] += __builtin_amdgcn_exp2f(cc[1]);
      L[2] += __builtin_amdgcn_exp2f(cc[2]); L[3] += __builtin_amdgcn_exp2f(cc[3]);
      Lacc[tsub] = L;
    }
  }

  // epilogue: LinvX[h][tc(64)][s(1024)][16] ; lane holds (s=ln, t=quad*4+r)
  const int sg = s0 + ws * 16 + ln;
  for (int tsub = 0; tsub < 8; tsub++) {
    const int tc = tq * 16 + wt * 8 + tsub;
    f32x4 L = Lacc[tsub];
    uint2 pk = make_uint2(
        pkbf(__builtin_amdgcn_rcpf(L[0]), __builtin_amdgcn_rcpf(L[1])),
        pkbf(__builtin_amdgcn_rcpf(L[2]), __builtin_amdgcn_rcpf(L[3])));
    *(uint2*)&LinvX[(((size_t)(h * 64 + tc)) * 1024 + sg) * 16 + quad * 4] = pk;
  }
}

// ---------------------------------------------------------------- attnB v3 (proven 54.8 us)
__global__ __launch_bounds__(256, 4) void attnB_kernel(
    const u16* __restrict__ Qb, const u16* __restrict__ Kb,
    const u16* __restrict__ VTb, const u16* __restrict__ LinvX,
    u16* __restrict__ hc) {
  __shared__ u16 Ks[2 * 32 * 64];   // 8 KB
  __shared__ u16 Vs[2 * 64 * 32];   // 8 KB
  __shared__ u16 Pp[4 * 2 * 16 * 40];
  const int tid = threadIdx.x;
  const int w = tid >> 6, lane = tid & 63;
  const int quad = lane >> 4, ln = lane & 15;
  const int h = blockIdx.x & 7, b = (blockIdx.x >> 3) & 15, sblk = blockIdx.x >> 7;
  const int ss0 = sblk * 128 + w * 32;
  const int krow = tid >> 3;
  const int ksw = ((tid & 7) ^ (krow & 7)) * 8;          // K staging swizzle
  const int vrow = tid >> 2;
  const int vsw = ((tid & 3) ^ ((tid >> 3) & 3)) * 8;    // V staging swizzle

  const u16* Kbase = Kb + (size_t)(h * 16 + b) * 65536;
  const u16* Vbase = VTb + (size_t)(h * 16 + b) * 65536;
  const u16* LinvH = LinvX + (size_t)h * 64 * 1024 * 16;

  f32x4 zero4 = {0.f, 0.f, 0.f, 0.f};
  bf16x8 qf[2][2];
  for (int a = 0; a < 2; a++) {
    const u16* Qp = Qb + ((size_t)(h * 16 + b) * 1024 + ss0 + a * 16 + ln) * 64;
    qf[a][0] = *(const bf16x8*)&Qp[quad * 8];
    qf[a][1] = *(const bf16x8*)&Qp[32 + quad * 8];
  }
  f32x4 o[2][4];
  for (int a = 0; a < 2; a++)
    for (int df = 0; df < 4; df++) o[a][df] = zero4;

  // prime it=0 into buf 0
  gload16(Kbase + (size_t)krow * 64 + ksw, (char*)Ks + w * 1024);
  gload16(Vbase + (size_t)vrow * 1024 + vsw, (char*)Vs + w * 1024);

  const int fsw = (quad ^ (ln & 7)) * 8;            // K fragment swizzle
  const int vfsw = (quad ^ ((ln >> 1) & 3)) * 8;    // V fragment swizzle

  for (int it = 0; it < 32; ++it) {
    const int cur = it & 1;
    const int t0 = it * 32;
    __syncthreads();   // drains buf[cur] loads; releases buf[cur^1] readers
    if (it < 31) {
      gload16(Kbase + (size_t)(t0 + 32 + krow) * 64 + ksw,
              (char*)Ks + (cur ^ 1) * 4096 + w * 1024);
      gload16(Vbase + (size_t)vrow * 1024 + t0 + 32 + vsw,
              (char*)Vs + (cur ^ 1) * 4096 + w * 1024);
    }
    bf16x8 kf[2][2], vf[4];
    for (int tsub = 0; tsub < 2; tsub++) {
      const u16* Kr = &Ks[cur * 2048 + (tsub * 16 + ln) * 64];
      kf[tsub][0] = *(const bf16x8*)&Kr[fsw];
      kf[tsub][1] = *(const bf16x8*)&Kr[fsw ^ 32];
    }
    for (int df = 0; df < 4; df++)
      vf[df] = *(const bf16x8*)&Vs[cur * 2048 + (df * 16 + ln) * 32 + vfsw];

    for (int a = 0; a < 2; a++) {
      for (int tsub = 0; tsub < 2; tsub++) {
        const int tc = it * 2 + tsub;
        ushort4 lin = *(const ushort4*)&LinvH[
            (((size_t)tc) * 1024 + ss0 + a * 16 + ln) * 16 + quad * 4];
        f32x4 cc = zero4;
        cc = __builtin_amdgcn_mfma_f32_16x16x32_bf16(kf[tsub][0], qf[a][0], cc, 0, 0, 0);
        cc = __builtin_amdgcn_mfma_f32_16x16x32_bf16(kf[tsub][1], qf[a][1], cc, 0, 0, 0);
        float p0 = __builtin_amdgcn_exp2f(cc[0]) * bf2f(lin.x);
        float p1 = __builtin_amdgcn_exp2f(cc[1]) * bf2f(lin.y);
        float p2 = __builtin_amdgcn_exp2f(cc[2]) * bf2f(lin.z);
        float p3 = __builtin_amdgcn_exp2f(cc[3]) * bf2f(lin.w);
        uint2 pk = make_uint2(pkbf_fast(p0, p1), pkbf_fast(p2, p3));
        *(uint2*)&Pp[(w * 2 + a) * 640 + ln * 40 + tsub * 16 + quad * 4] = pk;
      }
      bf16x8 pa = *(const bf16x8*)&Pp[(w * 2 + a) * 640 + ln * 40 + quad * 8];
      for (int df = 0; df < 4; df++)
        o[a][df] = __builtin_amdgcn_mfma_f32_16x16x32_bf16(pa, vf[df], o[a][df], 0, 0, 0);
    }
  }

  // epilogue: heads_cat [b*1024+s][h*64+d] bf16
  for (int a = 0; a < 2; a++) {
    for (int df = 0; df < 4; df++) {
      f32x4 c = o[a][df];
      for (int r = 0; r < 4; r++) {
        int sg = ss0 + a * 16 + quad * 4 + r;
        hc[((size_t)(b * 1024 + sg)) * 512 + h * 64 + df * 16 + ln] = f2bf(c[r]);
      }
    }
  }
}

// ---------------------------------------------------------------- bias + LN + LeakyReLU (bf16 Y input)
__global__ __launch_bounds__(256) void ln_kernel(
    const u16* __restrict__ Yb, const float* __restrict__ b_out,
    const float* __restrict__ gamma, const float* __restrict__ beta,
    float* __restrict__ out) {
  const int w = threadIdx.x >> 6, lane = threadIdx.x & 63;
  const int row = blockIdx.x * 4 + w;
  // lane owns 8 contiguous cols: two 8B bf16 loads
  ushort4 ya = *(const ushort4*)&Yb[(size_t)row * 512 + lane * 8];
  ushort4 yc = *(const ushort4*)&Yb[(size_t)row * 512 + lane * 8 + 4];
  float4 b0 = ((const float4*)b_out)[lane * 2], b1 = ((const float4*)b_out)[lane * 2 + 1];
  float v[8];
  v[0] = bf2f(ya.x) + b0.x; v[1] = bf2f(ya.y) + b0.y;
  v[2] = bf2f(ya.z) + b0.z; v[3] = bf2f(ya.w) + b0.w;
  v[4] = bf2f(yc.x) + b1.x; v[5] = bf2f(yc.y) + b1.y;
  v[6] = bf2f(yc.z) + b1.z; v[7] = bf2f(yc.w) + b1.w;
  float s = 0.f, s2 = 0.f;
  for (int j = 0; j < 8; j++) { s += v[j]; s2 += v[j] * v[j]; }
  for (int off = 32; off; off >>= 1) {
    s += __shfl_xor(s, off);
    s2 += __shfl_xor(s2, off);
  }
  float mean = s * (1.0f / 512.0f);
  float var = s2 * (1.0f / 512.0f) - mean * mean;
  float rs = rsqrtf(var + 1e-5f);
  float4 g0 = ((const float4*)gamma)[lane * 2], g1 = ((const float4*)gamma)[lane * 2 + 1];
  float4 e0 = ((const float4*)beta)[lane * 2], e1 = ((const float4*)beta)[lane * 2 + 1];
  float g[8] = {g0.x, g0.y, g0.z, g0.w, g1.x, g1.y, g1.z, g1.w};
  float e[8] = {e0.x, e0.y, e0.z, e0.w, e1.x, e1.y, e1.z, e1.w};
  float r[8];
  for (int j = 0; j < 8; j++) {
    float y = (v[j] - mean) * rs * g[j] + e[j];
    r[j] = y >= 0.f ? y : 0.1f * y;
  }
  float4 o0 = make_float4(r[0], r[1], r[2], r[3]);
  float4 o1 = make_float4(r[4], r[5], r[6], r[7]);
  ((float4*)out)[(size_t)row * 128 + lane * 2] = o0;
  ((float4*)out)[(size_t)row * 128 + lane * 2 + 1] = o1;
}

// ---------------------------------------------------------------- launch
extern "C" void kernel_launch(void* const* d_in, const int* in_sizes, int n_in,
                              void* d_out, int out_size, void* d_ws, size_t ws_size,
                              hipStream_t stream) {
  const float* x      = (const float*)d_in[0];
  const float* wq     = (const float*)d_in[1];
  const float* wk     = (const float*)d_in[2];
  const float* wv     = (const float*)d_in[3];
  const float* w_out  = (const float*)d_in[4];
  const float* b_out  = (const float*)d_in[5];
  const float* gamma  = (const float*)d_in[6];
  const float* beta   = (const float*)d_in[7];
  float* out = (float*)d_out;

  char* ws = (char*)d_ws;
  size_t off = 0;
  u16* xb  = (u16*)(ws + off); off += (size_t)MROWS * INDIM * 2;
  u16* W1T = (u16*)(ws + off); off += (size_t)3 * OUTDIM * INDIM * 2;
  u16* W2T = (u16*)(ws + off); off += (size_t)OUTDIM * INDIM * 2;
  u16* Qb  = (u16*)(ws + off); off += (size_t)HEADS * NBATCH * SDIM * DHEAD * 2;
  u16* Kb  = (u16*)(ws + off); off += (size_t)HEADS * NBATCH * SDIM * DHEAD * 2;
  u16* VTb = (u16*)(ws + off); off += (size_t)HEADS * NBATCH * SDIM * DHEAD * 2;
  u16* hc  = (u16*)(ws + off); off += (size_t)MROWS * OUTDIM * 2;
  u16* LinvX = (u16*)(ws + off);        // 16.8 MB; attnA->attnB only
  u16* Yb = LinvX;                      // aliased: gemm2 writes AFTER attnB reads (stream-ordered)

  prep_kernel<<<2304, 256, 0, stream>>>(x, wq, wk, wv, w_out, xb, W1T, W2T);
  gemm128<0><<<dim3(12, 128), 256, 0, stream>>>(xb, W1T, Qb, Kb, VTb, nullptr);
  attnA_kernel<<<512, 512, 0, stream>>>(Qb, Kb, LinvX);
  attnB_kernel<<<1024, 256, 0, stream>>>(Qb, Kb, VTb, LinvX, hc);
  gemm128<1><<<dim3(4, 128), 256, 0, stream>>>(hc, W2T, nullptr, nullptr, nullptr, Yb);
  ln_kernel<<<4096, 256, 0, stream>>>(Yb, b_out, gamma, beta, out);
}